// Round 3
// baseline (1056.887 us; speedup 1.0000x reference)
//
#include <hip/hip_runtime.h>
#include <cstdint>
#include <cstddef>

// ---------------------------------------------------------------------------
// GATv2 x2 + linear head on MI355X.
// CSR build (hist/scan/scatter -> sorted, src_sorted, dst_sorted) +
// one-time eattr shuffle into dst-sorted order (if ws allows) ->
// per-layer { fused dual linear, fully-streamed edge logits, single-pass
// node softmax+aggregate }, final linear. No float atomics.
// ---------------------------------------------------------------------------

__global__ void hist_kernel(const int* __restrict__ dst, int* __restrict__ deg, int E) {
    int e = blockIdx.x * blockDim.x + threadIdx.x;
    if (e < E) atomicAdd(&deg[dst[e]], 1);
}

// single-block exclusive scan, 1024 threads, 4 elems/thread/chunk
__global__ void scan_kernel(const int* __restrict__ deg, int* __restrict__ rowstart, int n) {
    __shared__ int wsum[16];
    int tid = threadIdx.x;
    int lane = tid & 63, wid = tid >> 6;
    int running = 0;
    const int CHUNK = 4096;
    for (int base = 0; base < n; base += CHUNK) {
        int v[4];
        int s = 0;
#pragma unroll
        for (int j = 0; j < 4; ++j) {
            int i = base + tid * 4 + j;
            v[j] = (i < n) ? deg[i] : 0;
            s += v[j];
        }
        int incl = s;
#pragma unroll
        for (int off = 1; off < 64; off <<= 1) {
            int t = __shfl_up(incl, off, 64);
            if (lane >= off) incl += t;
        }
        if (lane == 63) wsum[wid] = incl;
        __syncthreads();
        if (wid == 0) {
            int wv = (lane < 16) ? wsum[lane] : 0;
#pragma unroll
            for (int off = 1; off < 16; off <<= 1) {
                int t = __shfl_up(wv, off, 64);
                if (lane >= off) wv += t;
            }
            if (lane < 16) wsum[lane] = wv;
        }
        __syncthreads();
        int wave_excl = (wid == 0) ? 0 : wsum[wid - 1];
        int acc = running + wave_excl + (incl - s);
#pragma unroll
        for (int j = 0; j < 4; ++j) {
            int i = base + tid * 4 + j;
            if (i < n) rowstart[i] = acc;
            acc += v[j];
        }
        int total = wsum[15];
        __syncthreads();
        running += total;
    }
    if (tid == 0) rowstart[n] = running;
}

__global__ void scatter_kernel(const int* __restrict__ src, const int* __restrict__ dst,
                               const int* __restrict__ rowstart, int* __restrict__ cursor,
                               int* __restrict__ sorted, int* __restrict__ src_sorted,
                               int* __restrict__ dst_sorted, int E) {
    int e = blockIdx.x * blockDim.x + threadIdx.x;
    if (e < E) {
        int d = dst[e];
        int p = atomicAdd(&cursor[d], 1);
        int pos = rowstart[d] + p;
        sorted[pos] = e;
        src_sorted[pos] = src[e];
        dst_sorted[pos] = d;
    }
}

// eattr_sorted[p] = eattr[sorted[p]] ; gather-read, coalesced 64B-row write
__global__ void eattr_shuffle_kernel(const int* __restrict__ sorted,
                                     const float* __restrict__ eattr,
                                     float* __restrict__ eattr_sorted, int E) {
    int pidx = blockIdx.x * blockDim.x + threadIdx.x;
    if (pidx < E) {
        int e = sorted[pidx];
        const float4* s4 = (const float4*)&eattr[(size_t)e * 16];
        float4* d4 = (float4*)&eattr_sorted[(size_t)pidx * 16];
        float4 a = s4[0], b = s4[1], c = s4[2], d = s4[3];
        d4[0] = a; d4[1] = b; d4[2] = c; d4[3] = d;
    }
}

// yl = x@Wl+bl, yr = x@Wr+br in one pass over x; block = NPB*M threads
template <int K, int M, int NPB>
__global__ void linear2_kernel(const float* __restrict__ x,
                               const float* __restrict__ Wl, const float* __restrict__ bl,
                               const float* __restrict__ Wr, const float* __restrict__ br,
                               float* __restrict__ yl, float* __restrict__ yr, int n) {
    __shared__ float sx[NPB * K];
    int tid = threadIdx.x;
    int node0 = blockIdx.x * NPB;
    for (int i = tid; i < NPB * K; i += NPB * M) {
        int nn = node0 + i / K;
        sx[i] = (nn < n) ? x[(size_t)nn * K + (i % K)] : 0.f;
    }
    __syncthreads();
    int ln = tid / M, m = tid % M;
    int node = node0 + ln;
    if (node >= n) return;
    float accL = bl[m], accR = br[m];
#pragma unroll
    for (int k = 0; k < K; ++k) {
        float xv = sx[ln * K + k];
        accL = fmaf(xv, Wl[k * M + m], accL);
        accR = fmaf(xv, Wr[k * M + m], accR);
    }
    yl[(size_t)node * M + m] = accL;
    yr[(size_t)node * M + m] = accR;
}

// y[n,M] = x[n,K] @ W[K,M] + b ; block = NPB*M threads
template <int K, int M, int NPB>
__global__ void linear_kernel(const float* __restrict__ x, const float* __restrict__ W,
                              const float* __restrict__ b, float* __restrict__ y, int n) {
    __shared__ float sx[NPB * K];
    int tid = threadIdx.x;
    int node0 = blockIdx.x * NPB;
    for (int i = tid; i < NPB * K; i += NPB * M) {
        int nn = node0 + i / K;
        sx[i] = (nn < n) ? x[(size_t)nn * K + (i % K)] : 0.f;
    }
    __syncthreads();
    int ln = tid / M, m = tid % M;
    int node = node0 + ln;
    if (node >= n) return;
    float acc = b[m];
#pragma unroll
    for (int k = 0; k < K; ++k) acc = fmaf(sx[ln * K + k], W[k * M + m], acc);
    y[(size_t)node * M + m] = acc;
}

// Edge logits over dst-sorted edge order. 2 channels/lane; grid-stride waves.
// All non-gather operands are pure streams (addresses independent of loads).
template <int H, int C>
__global__ void edge_logits_sorted(const int* __restrict__ sorted,
                                   const int* __restrict__ src_sorted,
                                   const int* __restrict__ dst_sorted,
                                   const float* __restrict__ eattr,
                                   const float* __restrict__ eattr_sorted,  // may be null
                                   int use_stream,
                                   const float* __restrict__ We,   // [16, HC]
                                   const float* __restrict__ att,  // [HC]
                                   const float* __restrict__ xl, const float* __restrict__ xr,
                                   float* __restrict__ evals, int E) {
    constexpr int HC = H * C;
    constexpr int LPE = HC / 2;   // lanes per edge (2 ch each)
    constexpr int EPW = 64 / LPE; // edges per wave
    int lane = threadIdx.x & 63;
    int sub = lane / LPE;
    int j = lane % LPE;
    int ch0 = 2 * j;
    int head = ch0 / C;
    float2 wcol[16];
#pragma unroll
    for (int k = 0; k < 16; ++k) wcol[k] = *(const float2*)&We[k * HC + ch0];
    float2 a2 = *(const float2*)&att[ch0];

    int wave = (blockIdx.x * blockDim.x + threadIdx.x) >> 6;
    int nwaves = (gridDim.x * blockDim.x) >> 6;
    int ngroups = (E + EPW - 1) / EPW;
    for (int g = wave; g < ngroups; g += nwaves) {
        int p = g * EPW + sub;
        bool valid = (p < E);
        int pc = valid ? p : (E - 1);
        int s = src_sorted[pc];
        int d = dst_sorted[pc];
        const float4* ea4 = use_stream ? (const float4*)&eattr_sorted[(size_t)pc * 16]
                                       : (const float4*)&eattr[(size_t)sorted[pc] * 16];
        float4 e0 = ea4[0], e1 = ea4[1], e2 = ea4[2], e3 = ea4[3];
        float2 xlv = *(const float2*)&xl[(size_t)s * HC + ch0];
        float2 xrv = *(const float2*)&xr[(size_t)d * HC + ch0];
        float av[16] = {e0.x, e0.y, e0.z, e0.w, e1.x, e1.y, e1.z, e1.w,
                        e2.x, e2.y, e2.z, e2.w, e3.x, e3.y, e3.z, e3.w};
        float m0 = xlv.x + xrv.x;
        float m1 = xlv.y + xrv.y;
#pragma unroll
        for (int k = 0; k < 16; ++k) {
            m0 = fmaf(av[k], wcol[k].x, m0);
            m1 = fmaf(av[k], wcol[k].y, m1);
        }
        m0 = (m0 > 0.f) ? m0 : 0.2f * m0;
        m1 = (m1 > 0.f) ? m1 : 0.2f * m1;
        float v = m0 * a2.x + m1 * a2.y;
#pragma unroll
        for (int msk = 1; msk < 16; msk <<= 1) v += __shfl_xor(v, msk, 64);
        if (valid && (j & 15) == 0) evals[(size_t)p * H + head] = v;
    }
}

// Single-pass per-node softmax + weighted aggregation (+bias, ELU).
template <int H, int C>
__global__ void node_agg_sorted(const int* __restrict__ rowstart,
                                const int* __restrict__ src_sorted,
                                const float* __restrict__ evals,
                                const float* __restrict__ xl,
                                const float* __restrict__ bias,
                                float* __restrict__ out, int n) {
    constexpr int HC = H * C;
    constexpr int LPN = HC / 2;
    constexpr int NPW = 64 / LPN;
    int gt = blockIdx.x * blockDim.x + threadIdx.x;
    int wave = gt >> 6;
    int lane = threadIdx.x & 63;
    int sub = lane / LPN;
    int j = lane % LPN;
    int ch0 = 2 * j;
    int head = ch0 / C;
    int node = wave * NPW + sub;
    if (node >= n) return;
    int beg = rowstart[node], end = rowstart[node + 1];
    float denom = 0.f, acc0 = 0.f, acc1 = 0.f;
    for (int p = beg; p < end; ++p) {
        float w = __expf(evals[(size_t)p * H + head]);
        int s = src_sorted[p];
        float2 xv = *(const float2*)&xl[(size_t)s * HC + ch0];
        denom += w;
        acc0 = fmaf(xv.x, w, acc0);
        acc1 = fmaf(xv.y, w, acc1);
    }
    float2 b2 = *(const float2*)&bias[ch0];
    float inv = 1.f / (denom + 1e-16f);
    float o0 = acc0 * inv + b2.x;
    float o1 = acc1 * inv + b2.y;
    o0 = (o0 > 0.f) ? o0 : __expf(o0) - 1.f;
    o1 = (o1 > 0.f) ? o1 : __expf(o1) - 1.f;
    *(float2*)&out[(size_t)node * HC + ch0] = make_float2(o0, o1);
}

extern "C" void kernel_launch(void* const* d_in, const int* in_sizes, int n_in,
                              void* d_out, int out_size, void* d_ws, size_t ws_size,
                              hipStream_t stream) {
    const float* x     = (const float*)d_in[0];
    const int*   eidx  = (const int*)d_in[1];
    const float* eattr = (const float*)d_in[2];
    const float* W1l   = (const float*)d_in[3];
    const float* b1l   = (const float*)d_in[4];
    const float* W1r   = (const float*)d_in[5];
    const float* b1r   = (const float*)d_in[6];
    const float* W1e   = (const float*)d_in[7];
    const float* att1  = (const float*)d_in[8];
    const float* bias1 = (const float*)d_in[9];
    const float* W2l   = (const float*)d_in[10];
    const float* b2l   = (const float*)d_in[11];
    const float* W2r   = (const float*)d_in[12];
    const float* b2r   = (const float*)d_in[13];
    const float* W2e   = (const float*)d_in[14];
    const float* att2  = (const float*)d_in[15];
    const float* bias2 = (const float*)d_in[16];
    const float* Wlin  = (const float*)d_in[17];
    const float* blin  = (const float*)d_in[18];

    const int N = in_sizes[0] / 128;
    const int E = in_sizes[1] / 2;
    const int* src = eidx;
    const int* dst = eidx + E;

    char* p = (char*)d_ws;
    auto take = [&](size_t bytes) {
        char* r = p;
        p += (bytes + 255) & ~(size_t)255;
        return r;
    };
    int*   deg        = (int*)take((size_t)N * sizeof(int));
    int*   cursor     = (int*)take((size_t)N * sizeof(int));
    int*   rowstart   = (int*)take((size_t)(N + 1) * sizeof(int));
    int*   sorted     = (int*)take((size_t)E * sizeof(int));
    int*   src_sorted = (int*)take((size_t)E * sizeof(int));
    int*   dst_sorted = (int*)take((size_t)E * sizeof(int));
    float* A          = (float*)take((size_t)N * 64 * sizeof(float));  // xl
    float* B          = (float*)take((size_t)N * 64 * sizeof(float));  // xr
    float* Cbuf       = (float*)take((size_t)N * 64 * sizeof(float));  // h1 / h2
    float* Ebuf       = (float*)take((size_t)E * 2 * sizeof(float));   // logits (sorted order)

    // optional: eattr in dst-sorted order (102 MB) — only if workspace allows
    size_t used = (size_t)(p - (char*)d_ws);
    size_t ea_bytes = (size_t)E * 16 * sizeof(float);
    int use_stream = (ws_size >= used + ea_bytes + 512) ? 1 : 0;
    float* eattr_sorted = use_stream ? (float*)take(ea_bytes) : (float*)nullptr;

    // ---- CSR build ----
    hipMemsetAsync(deg, 0, (size_t)N * sizeof(int), stream);
    hipMemsetAsync(cursor, 0, (size_t)N * sizeof(int), stream);
    hist_kernel<<<(E + 255) / 256, 256, 0, stream>>>(dst, deg, E);
    scan_kernel<<<1, 1024, 0, stream>>>(deg, rowstart, N);
    scatter_kernel<<<(E + 255) / 256, 256, 0, stream>>>(src, dst, rowstart, cursor, sorted,
                                                        src_sorted, dst_sorted, E);
    if (use_stream)
        eattr_shuffle_kernel<<<(E + 255) / 256, 256, 0, stream>>>(sorted, eattr, eattr_sorted, E);

    const int EDGE_GRID = 2048;  // persistent grid-stride waves

    // ---- Layer 1: H=2, C=32 ----
    linear2_kernel<128, 64, 4><<<(N + 3) / 4, 256, 0, stream>>>(x, W1l, b1l, W1r, b1r, A, B, N);
    edge_logits_sorted<2, 32><<<EDGE_GRID, 256, 0, stream>>>(
        sorted, src_sorted, dst_sorted, eattr, eattr_sorted, use_stream, W1e, att1, A, B, Ebuf, E);
    node_agg_sorted<2, 32><<<((size_t)(N + 1) / 2 * 64 + 255) / 256, 256, 0, stream>>>(
        rowstart, src_sorted, Ebuf, A, bias1, Cbuf, N);

    // ---- Layer 2: H=1, C=32 ----
    linear2_kernel<64, 32, 8><<<(N + 7) / 8, 256, 0, stream>>>(Cbuf, W2l, b2l, W2r, b2r, A, B, N);
    edge_logits_sorted<1, 32><<<EDGE_GRID, 256, 0, stream>>>(
        sorted, src_sorted, dst_sorted, eattr, eattr_sorted, use_stream, W2e, att2, A, B, Ebuf, E);
    node_agg_sorted<1, 32><<<((size_t)(N + 3) / 4 * 64 + 255) / 256, 256, 0, stream>>>(
        rowstart, src_sorted, Ebuf, A, bias2, Cbuf, N);

    // ---- Final linear ----
    linear_kernel<32, 32, 8><<<(N + 7) / 8, 256, 0, stream>>>(Cbuf, Wlin, blin, (float*)d_out, N);
}

// Round 5
// 768.671 us; speedup vs baseline: 1.3750x; 1.3750x over previous
//
#include <hip/hip_runtime.h>
#include <cstdint>
#include <cstddef>

// ---------------------------------------------------------------------------
// GATv2 x2 + linear head on MI355X.
// CSR build (hist/scan/scatter -> rank[e], src_sorted) ->
// per-layer { register-tiled dual GEMM, edge logits streamed in ORIGINAL edge
// order (scatter-write logits to sorted pos via rank), single-pass node
// softmax+aggregate }, final linear. No float atomics.
// ---------------------------------------------------------------------------

__global__ void hist_kernel(const int* __restrict__ dst, int* __restrict__ deg, int E) {
    int e = blockIdx.x * blockDim.x + threadIdx.x;
    if (e < E) atomicAdd(&deg[dst[e]], 1);
}

// single-block exclusive scan, 1024 threads, 4 elems/thread/chunk
__global__ void scan_kernel(const int* __restrict__ deg, int* __restrict__ rowstart, int n) {
    __shared__ int wsum[16];
    int tid = threadIdx.x;
    int lane = tid & 63, wid = tid >> 6;
    int running = 0;
    const int CHUNK = 4096;
    for (int base = 0; base < n; base += CHUNK) {
        int v[4];
        int s = 0;
#pragma unroll
        for (int j = 0; j < 4; ++j) {
            int i = base + tid * 4 + j;
            v[j] = (i < n) ? deg[i] : 0;
            s += v[j];
        }
        int incl = s;
#pragma unroll
        for (int off = 1; off < 64; off <<= 1) {
            int t = __shfl_up(incl, off, 64);
            if (lane >= off) incl += t;
        }
        if (lane == 63) wsum[wid] = incl;
        __syncthreads();
        if (wid == 0) {
            int wv = (lane < 16) ? wsum[lane] : 0;
#pragma unroll
            for (int off = 1; off < 16; off <<= 1) {
                int t = __shfl_up(wv, off, 64);
                if (lane >= off) wv += t;
            }
            if (lane < 16) wsum[lane] = wv;
        }
        __syncthreads();
        int wave_excl = (wid == 0) ? 0 : wsum[wid - 1];
        int acc = running + wave_excl + (incl - s);
#pragma unroll
        for (int j = 0; j < 4; ++j) {
            int i = base + tid * 4 + j;
            if (i < n) rowstart[i] = acc;
            acc += v[j];
        }
        int total = wsum[15];
        __syncthreads();
        running += total;
    }
    if (tid == 0) rowstart[n] = running;
}

// rank[e] = sorted position of edge e; src_sorted[pos] = src[e]
__global__ void scatter_kernel(const int* __restrict__ src, const int* __restrict__ dst,
                               const int* __restrict__ rowstart, int* __restrict__ cursor,
                               int* __restrict__ rank, int* __restrict__ src_sorted, int E) {
    int e = blockIdx.x * blockDim.x + threadIdx.x;
    if (e < E) {
        int d = dst[e];
        int p = atomicAdd(&cursor[d], 1);
        int pos = rowstart[d] + p;
        rank[e] = pos;
        src_sorted[pos] = src[e];
    }
}

__device__ __forceinline__ void fma4(float4& a, float s, const float4& wv) {
    a.x = fmaf(s, wv.x, a.x);
    a.y = fmaf(s, wv.y, a.y);
    a.z = fmaf(s, wv.z, a.z);
    a.w = fmaf(s, wv.w, a.w);
}

// Register-tiled dual GEMM: yl = x@Wl+bl, yr = x@Wr+br.
// BLOCK threads; thread tile = 8 nodes x 4 m; x tile in LDS; W from global.
template <int K, int Mh, int BLOCK>
__global__ __launch_bounds__(BLOCK) void gemm_dual(
    const float* __restrict__ x,
    const float* __restrict__ Wl, const float* __restrict__ bl,
    const float* __restrict__ Wr, const float* __restrict__ br,
    float* __restrict__ yl, float* __restrict__ yr, int n) {
    constexpr int M = 2 * Mh;
    constexpr int MI = M / 4;        // m-threads
    constexpr int NG = BLOCK / MI;   // node groups
    constexpr int NT = NG * 8;       // nodes per block
    __shared__ float xs[NT * K];
    int tid = threadIdx.x;
    int node0 = blockIdx.x * NT;
    // stage x tile (coalesced float4)
    for (int i = tid * 4; i < NT * K; i += BLOCK * 4) {
        int nn = i / K, k = i % K;
        float4 v = make_float4(0.f, 0.f, 0.f, 0.f);
        if (node0 + nn < n) v = *(const float4*)&x[(size_t)(node0 + nn) * K + k];
        *(float4*)&xs[nn * K + k] = v;
    }
    __syncthreads();
    int mi = tid % MI, ng = tid / MI;
    int m0 = mi * 4, nb = ng * 8;
    const float* Wsel;
    const float* bsel;
    float* ysel;
    int ms;
    if (m0 < Mh) { Wsel = Wl; bsel = bl; ysel = yl; ms = m0; }
    else         { Wsel = Wr; bsel = br; ysel = yr; ms = m0 - Mh; }
    float4 bias = *(const float4*)&bsel[ms];
    float4 acc[8];
#pragma unroll
    for (int nn = 0; nn < 8; ++nn) acc[nn] = bias;
    for (int k0 = 0; k0 < K; k0 += 4) {
        float4 wv0 = *(const float4*)&Wsel[(size_t)(k0 + 0) * Mh + ms];
        float4 wv1 = *(const float4*)&Wsel[(size_t)(k0 + 1) * Mh + ms];
        float4 wv2 = *(const float4*)&Wsel[(size_t)(k0 + 2) * Mh + ms];
        float4 wv3 = *(const float4*)&Wsel[(size_t)(k0 + 3) * Mh + ms];
#pragma unroll
        for (int nn = 0; nn < 8; ++nn) {
            float4 xv = *(const float4*)&xs[(nb + nn) * K + k0];
            fma4(acc[nn], xv.x, wv0);
            fma4(acc[nn], xv.y, wv1);
            fma4(acc[nn], xv.z, wv2);
            fma4(acc[nn], xv.w, wv3);
        }
    }
#pragma unroll
    for (int nn = 0; nn < 8; ++nn) {
        int node = node0 + nb + nn;
        if (node < n) *(float4*)&ysel[(size_t)node * Mh + ms] = acc[nn];
    }
}

// y[n,M] = x[n,K] @ W[K,M] + b ; block = NPB*M threads (small final layer)
template <int K, int M, int NPB>
__global__ void linear_kernel(const float* __restrict__ x, const float* __restrict__ W,
                              const float* __restrict__ b, float* __restrict__ y, int n) {
    __shared__ float sx[NPB * K];
    int tid = threadIdx.x;
    int node0 = blockIdx.x * NPB;
    for (int i = tid; i < NPB * K; i += NPB * M) {
        int nn = node0 + i / K;
        sx[i] = (nn < n) ? x[(size_t)nn * K + (i % K)] : 0.f;
    }
    __syncthreads();
    int ln = tid / M, m = tid % M;
    int node = node0 + ln;
    if (node >= n) return;
    float acc = b[m];
#pragma unroll
    for (int k = 0; k < K; ++k) acc = fmaf(sx[ln * K + k], W[k * M + m], acc);
    y[(size_t)node * M + m] = acc;
}

// Edge logits in ORIGINAL edge order: src/dst/eattr/rank are pure streams;
// xl/xr are 1-level gathers. Scatter-writes logit to sorted position rank[e].
template <int H, int C>
__global__ void edge_logits_stream(const int* __restrict__ src, const int* __restrict__ dst,
                                   const float* __restrict__ eattr,
                                   const int* __restrict__ rank,
                                   const float* __restrict__ We,   // [16, HC]
                                   const float* __restrict__ att,  // [HC]
                                   const float* __restrict__ xl, const float* __restrict__ xr,
                                   float* __restrict__ evals, int E) {
    constexpr int HC = H * C;
    constexpr int LPE = HC / 2;   // lanes per edge (2 ch each)
    constexpr int EPW = 64 / LPE; // edges per wave
    int lane = threadIdx.x & 63;
    int sub = lane / LPE;
    int j = lane % LPE;
    int ch0 = 2 * j;
    int head = ch0 / C;
    float2 wcol[16];
#pragma unroll
    for (int k = 0; k < 16; ++k) wcol[k] = *(const float2*)&We[k * HC + ch0];
    float2 a2 = *(const float2*)&att[ch0];

    int wave = (blockIdx.x * blockDim.x + threadIdx.x) >> 6;
    int nwaves = (gridDim.x * blockDim.x) >> 6;
    int ngroups = (E + EPW - 1) / EPW;
    for (int g = wave; g < ngroups; g += nwaves) {
        int e = g * EPW + sub;
        bool valid = (e < E);
        int ec = valid ? e : (E - 1);
        int s = src[ec];
        int d = dst[ec];
        int rk = rank[ec];
        const float4* ea4 = (const float4*)&eattr[(size_t)ec * 16];
        float4 e0 = ea4[0], e1 = ea4[1], e2 = ea4[2], e3 = ea4[3];
        float2 xlv = *(const float2*)&xl[(size_t)s * HC + ch0];
        float2 xrv = *(const float2*)&xr[(size_t)d * HC + ch0];
        float av[16] = {e0.x, e0.y, e0.z, e0.w, e1.x, e1.y, e1.z, e1.w,
                        e2.x, e2.y, e2.z, e2.w, e3.x, e3.y, e3.z, e3.w};
        float m0 = xlv.x + xrv.x;
        float m1 = xlv.y + xrv.y;
#pragma unroll
        for (int k = 0; k < 16; ++k) {
            m0 = fmaf(av[k], wcol[k].x, m0);
            m1 = fmaf(av[k], wcol[k].y, m1);
        }
        m0 = (m0 > 0.f) ? m0 : 0.2f * m0;
        m1 = (m1 > 0.f) ? m1 : 0.2f * m1;
        float v = m0 * a2.x + m1 * a2.y;
#pragma unroll
        for (int msk = 1; msk < 16; msk <<= 1) v += __shfl_xor(v, msk, 64);
        if (valid && (j & 15) == 0) evals[(size_t)rk * H + head] = v;
    }
}

// Single-pass per-node softmax + weighted aggregation (+bias, ELU).
// evals/src_sorted are streams; xl is a 1-level gather.
template <int H, int C>
__global__ void node_agg_sorted(const int* __restrict__ rowstart,
                                const int* __restrict__ src_sorted,
                                const float* __restrict__ evals,
                                const float* __restrict__ xl,
                                const float* __restrict__ bias,
                                float* __restrict__ out, int n) {
    constexpr int HC = H * C;
    constexpr int LPN = HC / 2;
    constexpr int NPW = 64 / LPN;
    int gt = blockIdx.x * blockDim.x + threadIdx.x;
    int wave = gt >> 6;
    int lane = threadIdx.x & 63;
    int sub = lane / LPN;
    int j = lane % LPN;
    int ch0 = 2 * j;
    int head = ch0 / C;
    int node = wave * NPW + sub;
    if (node >= n) return;
    int beg = rowstart[node], end = rowstart[node + 1];
    float denom = 0.f, acc0 = 0.f, acc1 = 0.f;
    for (int p = beg; p < end; ++p) {
        float w = __expf(evals[(size_t)p * H + head]);
        int s = src_sorted[p];
        float2 xv = *(const float2*)&xl[(size_t)s * HC + ch0];
        denom += w;
        acc0 = fmaf(xv.x, w, acc0);
        acc1 = fmaf(xv.y, w, acc1);
    }
    float2 b2 = *(const float2*)&bias[ch0];
    float inv = 1.f / (denom + 1e-16f);
    float o0 = acc0 * inv + b2.x;
    float o1 = acc1 * inv + b2.y;
    o0 = (o0 > 0.f) ? o0 : __expf(o0) - 1.f;
    o1 = (o1 > 0.f) ? o1 : __expf(o1) - 1.f;
    *(float2*)&out[(size_t)node * HC + ch0] = make_float2(o0, o1);
}

extern "C" void kernel_launch(void* const* d_in, const int* in_sizes, int n_in,
                              void* d_out, int out_size, void* d_ws, size_t ws_size,
                              hipStream_t stream) {
    const float* x     = (const float*)d_in[0];
    const int*   eidx  = (const int*)d_in[1];
    const float* eattr = (const float*)d_in[2];
    const float* W1l   = (const float*)d_in[3];
    const float* b1l   = (const float*)d_in[4];
    const float* W1r   = (const float*)d_in[5];
    const float* b1r   = (const float*)d_in[6];
    const float* W1e   = (const float*)d_in[7];
    const float* att1  = (const float*)d_in[8];
    const float* bias1 = (const float*)d_in[9];
    const float* W2l   = (const float*)d_in[10];
    const float* b2l   = (const float*)d_in[11];
    const float* W2r   = (const float*)d_in[12];
    const float* b2r   = (const float*)d_in[13];
    const float* W2e   = (const float*)d_in[14];
    const float* att2  = (const float*)d_in[15];
    const float* bias2 = (const float*)d_in[16];
    const float* Wlin  = (const float*)d_in[17];
    const float* blin  = (const float*)d_in[18];

    const int N = in_sizes[0] / 128;
    const int E = in_sizes[1] / 2;
    const int* src = eidx;
    const int* dst = eidx + E;

    char* p = (char*)d_ws;
    auto take = [&](size_t bytes) {
        char* r = p;
        p += (bytes + 255) & ~(size_t)255;
        return r;
    };
    int*   deg        = (int*)take((size_t)N * sizeof(int));
    int*   cursor     = (int*)take((size_t)N * sizeof(int));
    int*   rowstart   = (int*)take((size_t)(N + 1) * sizeof(int));
    int*   rank       = (int*)take((size_t)E * sizeof(int));
    int*   src_sorted = (int*)take((size_t)E * sizeof(int));
    float* A          = (float*)take((size_t)N * 64 * sizeof(float));  // xl
    float* B          = (float*)take((size_t)N * 64 * sizeof(float));  // xr
    float* Cbuf       = (float*)take((size_t)N * 64 * sizeof(float));  // h1 / h2
    float* Ebuf       = (float*)take((size_t)E * 2 * sizeof(float));   // logits (sorted order)

    // ---- CSR build ----
    (void)hipMemsetAsync(deg, 0, (size_t)N * sizeof(int), stream);
    (void)hipMemsetAsync(cursor, 0, (size_t)N * sizeof(int), stream);
    hist_kernel<<<(E + 255) / 256, 256, 0, stream>>>(dst, deg, E);
    scan_kernel<<<1, 1024, 0, stream>>>(deg, rowstart, N);
    scatter_kernel<<<(E + 255) / 256, 256, 0, stream>>>(src, dst, rowstart, cursor, rank,
                                                        src_sorted, E);

    const int EDGE_GRID = 2048;

    // ---- Layer 1: H=2, C=32 ----
    gemm_dual<128, 64, 256><<<(N + 63) / 64, 256, 0, stream>>>(x, W1l, b1l, W1r, b1r, A, B, N);
    edge_logits_stream<2, 32><<<EDGE_GRID, 256, 0, stream>>>(src, dst, eattr, rank, W1e, att1, A,
                                                             B, Ebuf, E);
    node_agg_sorted<2, 32><<<((size_t)(N + 1) / 2 * 64 + 255) / 256, 256, 0, stream>>>(
        rowstart, src_sorted, Ebuf, A, bias1, Cbuf, N);

    // ---- Layer 2: H=1, C=32 ----
    gemm_dual<64, 32, 256><<<(N + 127) / 128, 256, 0, stream>>>(Cbuf, W2l, b2l, W2r, b2r, A, B, N);
    edge_logits_stream<1, 32><<<EDGE_GRID, 256, 0, stream>>>(src, dst, eattr, rank, W2e, att2, A,
                                                             B, Ebuf, E);
    node_agg_sorted<1, 32><<<((size_t)(N + 3) / 4 * 64 + 255) / 256, 256, 0, stream>>>(
        rowstart, src_sorted, Ebuf, A, bias2, Cbuf, N);

    // ---- Final linear ----
    linear_kernel<32, 32, 8><<<(N + 7) / 8, 256, 0, stream>>>(Cbuf, Wlin, blin, (float*)d_out, N);
}